// Round 4
// baseline (353.046 us; speedup 1.0000x reference)
//
#include <hip/hip_runtime.h>
#include <hip/hip_bf16.h>

// MultiheadAttention: S=2048, B=4, E=1024, H=16, D=64
//   K0   detect input dtype (fp32 vs bf16) -> flag
//   K0b  single merged convert kernel -> canonical bf16 in ws
//   K1   qkv GEMM (m97-style).  Q pre-scaled by 0.125*log2(e)  (log2-domain softmax)
//   K2   flash attention, T12 structure, ZERO LDS / ZERO barriers:
//        K and V fragments read directly from global (K/V per head = 256 KB,
//        L2-fit; each 128B line fully consumed per tile -> L1-served).
//        Swapped QK^T (S^T via mfma(K,Q)), in-register softmax,
//        PV as O^T = V^T P^T.  32x32x16 MFMAs.  shfl_xor lane-half exchange
//        (numerically verified in R3).
//   K3   out-proj GEMM

typedef __attribute__((ext_vector_type(8))) short bf16x8;
typedef __attribute__((ext_vector_type(4))) float floatx4;
typedef __attribute__((ext_vector_type(16))) float floatx16;
typedef __attribute__((ext_vector_type(4))) unsigned int uintx4;

#define S_LEN 2048
#define EMB   1024
#define DHEAD 64

static __device__ __forceinline__ unsigned short f2bf(float x) {
    return __builtin_bit_cast(unsigned short, __float2bfloat16(x));
}

static __device__ __forceinline__ unsigned pack_bf16(float a, float b) {
    // dword[15:0] = bf16(a) (elem 2i), dword[31:16] = bf16(b) (elem 2i+1), RNE
    return (unsigned)f2bf(a) | ((unsigned)f2bf(b) << 16);
}

// ---------------------------------------------------------------------------
static __device__ __forceinline__ void dma16(const void* g, void* l) {
    __builtin_amdgcn_global_load_lds(
        (const __attribute__((address_space(1))) unsigned int*)(unsigned long long)g,
        (__attribute__((address_space(3))) unsigned int*)(unsigned int)(unsigned long long)l,
        16, 0, 0);
}

// ---------------------------------------------------------------------------
// K0: dtype detection (fp32 read as u16 words has ~48% with exponent>=132)
// ---------------------------------------------------------------------------
__global__ void detect_kernel(const unsigned short* __restrict__ q, int* __restrict__ flag) {
    __shared__ int cnt;
    if (threadIdx.x == 0) cnt = 0;
    __syncthreads();
    int local = 0;
    for (int i = threadIdx.x; i < 4096; i += 256) {
        unsigned short u = q[i];
        int e = (u >> 7) & 0xFF;
        if (e >= 132) local++;
    }
    atomicAdd(&cnt, local);
    __syncthreads();
    if (threadIdx.x == 0) *flag = (cnt > 100) ? 1 : 0;
}

// ---------------------------------------------------------------------------
// K0b: merged convert of all 5 inputs, vectorized x4.
// ---------------------------------------------------------------------------
__global__ void convert_all_kernel(
    const void* __restrict__ s0, const void* __restrict__ s1, const void* __restrict__ s2,
    const void* __restrict__ s3, const void* __restrict__ s4,
    __hip_bfloat16* __restrict__ d0, __hip_bfloat16* __restrict__ d1, __hip_bfloat16* __restrict__ d2,
    __hip_bfloat16* __restrict__ d3, __hip_bfloat16* __restrict__ d4,
    const int* __restrict__ flag)
{
    const int mode = *flag;
    const int c0 = 2097152, c1 = c0 + 786432, c2 = c1 + 768, c3 = c2 + 262144, c4 = c3 + 256;
    int i = blockIdx.x * blockDim.x + threadIdx.x;
    const int stride = gridDim.x * blockDim.x;
    for (; i < c4; i += stride) {
        const void* s; __hip_bfloat16* d; int off;
        if (i < c0)      { s = s0; d = d0; off = i; }
        else if (i < c1) { s = s1; d = d1; off = i - c0; }
        else if (i < c2) { s = s2; d = d2; off = i - c1; }
        else if (i < c3) { s = s3; d = d3; off = i - c2; }
        else             { s = s4; d = d4; off = i - c3; }
        if (mode) {
            float4 v = ((const float4*)s)[off];
            ushort4 o;
            o.x = f2bf(v.x); o.y = f2bf(v.y); o.z = f2bf(v.z); o.w = f2bf(v.w);
            ((ushort4*)d)[off] = o;
        } else {
            ((ushort4*)d)[off] = ((const ushort4*)s)[off];
        }
    }
}

// ---------------------------------------------------------------------------
// GEMM core (m97 structure): 128x128 tile, BK=64, XOR chunk swizzle LDS.
// ---------------------------------------------------------------------------
#define GEMM_STAGE(As, Bs, Aptr, Bptr, ldA, ldB)                                       \
    {                                                                                  \
        const int srow = (l >> 3);                                                     \
        const int cG   = ((l & 7) ^ srow) * 8;                                         \
        _Pragma("unroll")                                                              \
        for (int j = 0; j < 4; j++) {                                                  \
            const int r0 = wave * 32 + j * 8;                                          \
            dma16(Aptr + (size_t)(r0 + srow) * ldA + cG, &As[r0][0]);                  \
            dma16(Bptr + (size_t)(r0 + srow) * ldB + cG, &Bs[r0][0]);                  \
        }                                                                              \
    }

__global__ __launch_bounds__(256) void qkv_gemm_kernel(
    const __hip_bfloat16* __restrict__ X,
    const __hip_bfloat16* __restrict__ W,
    const __hip_bfloat16* __restrict__ bias,
    __hip_bfloat16* __restrict__ Qws,
    __hip_bfloat16* __restrict__ Kws,
    __hip_bfloat16* __restrict__ Vws)
{
    __shared__ alignas(16) __hip_bfloat16 As[128][64];
    __shared__ alignas(16) __hip_bfloat16 Bs[128][64];

    const int t    = threadIdx.x;
    const int l    = t & 63;
    const int wave = t >> 6;
    const int l15  = l & 15;
    const int quad = l >> 4;
    const int wr   = (wave >> 1) * 64;
    const int wc   = (wave & 1) * 64;
    const int rowBase = blockIdx.x * 128;
    const int colBase = blockIdx.y * 128;

    floatx4 acc[4][4] = {};

    for (int k0 = 0; k0 < EMB; k0 += 64) {
        __syncthreads();
        const __hip_bfloat16* Ap = X + (size_t)rowBase * EMB + k0;
        const __hip_bfloat16* Bp = W + (size_t)colBase * EMB + k0;
        GEMM_STAGE(As, Bs, Ap, Bp, EMB, EMB)
        __syncthreads();
#pragma unroll
        for (int ks = 0; ks < 2; ks++) {
            bf16x8 af[4], bfr[4];
#pragma unroll
            for (int ti = 0; ti < 4; ti++) {
                const int rA = wr + ti * 16 + l15;
                af[ti] = *(const bf16x8*)(&As[rA][(((ks * 4 + quad) ^ (rA & 7)) * 8)]);
            }
#pragma unroll
            for (int tj = 0; tj < 4; tj++) {
                const int rB = wc + tj * 16 + l15;
                bfr[tj] = *(const bf16x8*)(&Bs[rB][(((ks * 4 + quad) ^ (rB & 7)) * 8)]);
            }
#pragma unroll
            for (int ti = 0; ti < 4; ti++)
#pragma unroll
                for (int tj = 0; tj < 4; tj++)
                    acc[ti][tj] = __builtin_amdgcn_mfma_f32_16x16x32_bf16(
                        af[ti], bfr[tj], acc[ti][tj], 0, 0, 0);
        }
    }

    // Q scale: 1/sqrt(64) * log2(e)  (softmax runs in log2 domain)
    const float QSCALE = 0.125f * 1.44269504088896f;
#pragma unroll
    for (int tj = 0; tj < 4; tj++) {
        const int col = colBase + wc + tj * 16 + l15;   // f in [0,3072)
        const int sec = col >> 10;                      // 0=Q 1=K 2=V
        const int e   = col & 1023;
        const int h   = e >> 6;
        const int d   = e & 63;
        const float bv = __bfloat162float(bias[col]);
#pragma unroll
        for (int ti = 0; ti < 4; ti++) {
#pragma unroll
            for (int r = 0; r < 4; r++) {
                const int row = rowBase + wr + ti * 16 + quad * 4 + r;  // s*4+b
                const int s  = row >> 2;
                const int b  = row & 3;
                const int nh = b * 16 + h;
                const float val = acc[ti][tj][r] + bv;
                if (sec == 0) {
                    Qws[((size_t)nh * S_LEN + s) * DHEAD + d] = __float2bfloat16(val * QSCALE);
                } else if (sec == 1) {
                    Kws[((size_t)nh * S_LEN + s) * DHEAD + d] = __float2bfloat16(val);
                } else {
                    Vws[((size_t)nh * DHEAD + d) * S_LEN + s] = __float2bfloat16(val);
                }
            }
        }
    }
}

// ---------------------------------------------------------------------------
// K2: flash attention, T12 in-register softmax, 32x32x16 MFMA, NO LDS/barriers.
// Block = (head n, 256 q-rows), 4 independent waves x 64 q each.
//
// QK^T swapped:  S^T = mfma(A=K[key][d], B=Q^T[d][q])
//   C layout (HW-verified m74/m101): col = lane&31 = q,
//   row(key) = (reg&3) + 8*(reg>>2) + 4*(lane>>5)
// K/V fragments read directly from global (same per-lane fragment indexing
// as the Q read, which is numerically proven).  K/V per head = 256 KB (L2-fit);
// each 128-B row-line is fully consumed by the 8/16 fragment reads per tile,
// so L1 serves most re-reads; no staging needed (m169 pattern).
// P^T B-operand built in-register (verified R3): pack bf16 pairs, exchange
// lane-halves with __shfl_xor(,32), per-lane select.
// PV:  O^T = mfma(A=V^T[d][key], B=P^T[key][q]).
// ---------------------------------------------------------------------------
__global__ __launch_bounds__(256, 2) void attn_kernel(
    const __hip_bfloat16* __restrict__ Qws,
    const __hip_bfloat16* __restrict__ Kws,
    const __hip_bfloat16* __restrict__ Vws,
    __hip_bfloat16* __restrict__ AOut)
{
    const int n  = blockIdx.x;        // 0..63 (= b*16+h)
    const int q0 = blockIdx.y * 256;
    const int t    = threadIdx.x;
    const int l    = t & 63;
    const int wave = t >> 6;
    const int l31  = l & 31;
    const int hi   = l >> 5;

    // Q B-operand frags: qb[qt][ds]: col(q) = l31, k(d) = ds*16 + hi*8 + j
    bf16x8 qb[2][4];
#pragma unroll
    for (int qt = 0; qt < 2; qt++)
#pragma unroll
        for (int ds = 0; ds < 4; ds++)
            qb[qt][ds] = *(const bf16x8*)(Qws +
                ((size_t)n * S_LEN + q0 + wave * 64 + qt * 32 + l31) * DHEAD + ds * 16 + hi * 8);

    // base pointers for this head's K (row = key) and V^T (row = d)
    const __hip_bfloat16* Kn = Kws + (size_t)n * S_LEN * DHEAD;   // [key][d]
    const __hip_bfloat16* Vn = Vws + (size_t)n * DHEAD * S_LEN;   // [d][key]

    floatx16 o[2][2] = {};   // o[dt][qt] = O^T tile (32 d x 32 q)
    float lsum[2] = {};      // per-lane partial softmax denominator per q-tile

    for (int kt = 0; kt < 32; kt++) {
        const int key0 = kt * 64;

        // K A-operand frags straight from global:
        //   kb[kt2][ds]: row(key) = key0 + kt2*32 + l31, k(d) = ds*16 + hi*8 + j
        bf16x8 kb[2][4];
#pragma unroll
        for (int kt2 = 0; kt2 < 2; kt2++)
#pragma unroll
            for (int ds = 0; ds < 4; ds++)
                kb[kt2][ds] = *(const bf16x8*)(Kn +
                    (size_t)(key0 + kt2 * 32 + l31) * DHEAD + ds * 16 + hi * 8);

        // V^T A-operand frags straight from global (issued early, consumed by PV):
        //   va[dt][kslab]: row(d) = dt*32 + l31, k(key) = key0 + kslab*16 + hi*8 + j
        bf16x8 va[2][4];
#pragma unroll
        for (int dt = 0; dt < 2; dt++)
#pragma unroll
            for (int kslab = 0; kslab < 4; kslab++)
                va[dt][kslab] = *(const bf16x8*)(Vn +
                    (size_t)(dt * 32 + l31) * S_LEN + key0 + kslab * 16 + hi * 8);

        // QK^T + in-register softmax, per 32-q tile
        bf16x8 pa[2][4];   // pa[qt][kslab]: P^T B-frags, kslab = 16 keys
#pragma unroll
        for (int qt = 0; qt < 2; qt++) {
            floatx16 sacc[2] = {};
            __builtin_amdgcn_s_setprio(1);
#pragma unroll
            for (int ds = 0; ds < 4; ds++)
#pragma unroll
                for (int kt2 = 0; kt2 < 2; kt2++)
                    sacc[kt2] = __builtin_amdgcn_mfma_f32_32x32x16_bf16(
                        kb[kt2][ds], qb[qt][ds], sacc[kt2], 0, 0, 0);
            __builtin_amdgcn_s_setprio(0);

#pragma unroll
            for (int kt2 = 0; kt2 < 2; kt2++) {
                float pv[16];
#pragma unroll
                for (int r = 0; r < 16; r++)
                    pv[r] = __builtin_amdgcn_exp2f(sacc[kt2][r]);
                lsum[qt] += (((pv[0] + pv[1]) + (pv[2] + pv[3])) + ((pv[4] + pv[5]) + (pv[6] + pv[7])))
                          + (((pv[8] + pv[9]) + (pv[10] + pv[11])) + ((pv[12] + pv[13]) + (pv[14] + pv[15])));
                // Lane key inventory (base = kt2*32 + sl*16):
                //   hi=0 lane: keys base+{0..3} = pv[b..b+3],  base+{8..11}  = pv[b+4..b+7]
                //   hi=1 lane: keys base+{4..7} = pv[b..b+3],  base+{12..15} = pv[b+4..b+7]
                // B-frag word w needs: lo lanes keys base+2w,2w+1; hi lanes base+8+2w,8+2w+1
#pragma unroll
                for (int sl = 0; sl < 2; sl++) {
                    const int b = sl * 8;
                    unsigned lo01 = pack_bf16(pv[b + 0], pv[b + 1]);
                    unsigned lo23 = pack_bf16(pv[b + 2], pv[b + 3]);
                    unsigned hi01 = pack_bf16(pv[b + 4], pv[b + 5]);
                    unsigned hi23 = pack_bf16(pv[b + 6], pv[b + 7]);
                    unsigned p_lo01 = __shfl_xor(lo01, 32);
                    unsigned p_lo23 = __shfl_xor(lo23, 32);
                    unsigned p_hi01 = __shfl_xor(hi01, 32);
                    unsigned p_hi23 = __shfl_xor(hi23, 32);
                    uintx4 w;
                    w[0] = hi ? p_hi01 : lo01;   // keys base+0,1  / base+8,9
                    w[1] = hi ? p_hi23 : lo23;   // keys base+2,3  / base+10,11
                    w[2] = hi ? hi01 : p_lo01;   // keys base+4,5  / base+12,13
                    w[3] = hi ? hi23 : p_lo23;   // keys base+6,7  / base+14,15
                    pa[qt][kt2 * 2 + sl] = __builtin_bit_cast(bf16x8, w);
                }
            }
        }

        // PV: O^T(64d x 64q) += V^T(64d x 64k) @ P^T(64k x 64q)
        __builtin_amdgcn_s_setprio(1);
#pragma unroll
        for (int kslab = 0; kslab < 4; kslab++)
#pragma unroll
            for (int dt = 0; dt < 2; dt++)
#pragma unroll
                for (int qt = 0; qt < 2; qt++)
                    o[dt][qt] = __builtin_amdgcn_mfma_f32_32x32x16_bf16(
                        va[dt][kslab], pa[qt][kslab], o[dt][qt], 0, 0, 0);
        __builtin_amdgcn_s_setprio(0);
    }

    // epilogue: combine hi/lo denominator halves, normalize, pack 4-wide stores
    const int bb  = n >> 4;
    const int h64 = (n & 15) * 64;
#pragma unroll
    for (int qt = 0; qt < 2; qt++) {
        const float denom = lsum[qt] + __shfl_xor(lsum[qt], 32);
        const float linv = 1.0f / denom;
        const int q = q0 + wave * 64 + qt * 32 + l31;
#pragma unroll
        for (int dt = 0; dt < 2; dt++) {
#pragma unroll
            for (int g = 0; g < 4; g++) {
                const int d = dt * 32 + g * 8 + hi * 4;  // regs 4g..4g+3 -> d..d+3
                ushort4 w;
                w.x = f2bf(o[dt][qt][4 * g + 0] * linv);
                w.y = f2bf(o[dt][qt][4 * g + 1] * linv);
                w.z = f2bf(o[dt][qt][4 * g + 2] * linv);
                w.w = f2bf(o[dt][qt][4 * g + 3] * linv);
                *(ushort4*)(AOut + ((size_t)q * 4 + bb) * EMB + h64 + d) = w;
            }
        }
    }
}

// ---------------------------------------------------------------------------
// K3: out-projection GEMM, output fp32 or bf16 per flag.
// ---------------------------------------------------------------------------
__global__ __launch_bounds__(256) void out_gemm_kernel(
    const __hip_bfloat16* __restrict__ A,
    const __hip_bfloat16* __restrict__ W,
    const __hip_bfloat16* __restrict__ bias,
    void* __restrict__ out,
    const int* __restrict__ flag)
{
    __shared__ alignas(16) __hip_bfloat16 As[128][64];
    __shared__ alignas(16) __hip_bfloat16 Bs[128][64];

    const int t    = threadIdx.x;
    const int l    = t & 63;
    const int wave = t >> 6;
    const int l15  = l & 15;
    const int quad = l >> 4;
    const int wr   = (wave >> 1) * 64;
    const int wc   = (wave & 1) * 64;
    const int rowBase = blockIdx.x * 128;
    const int colBase = blockIdx.y * 128;
    const int mode = *flag;

    floatx4 acc[4][4] = {};

    for (int k0 = 0; k0 < EMB; k0 += 64) {
        __syncthreads();
        const __hip_bfloat16* Ap = A + (size_t)rowBase * EMB + k0;
        const __hip_bfloat16* Bp = W + (size_t)colBase * EMB + k0;
        GEMM_STAGE(As, Bs, Ap, Bp, EMB, EMB)
        __syncthreads();
#pragma unroll
        for (int ks = 0; ks < 2; ks++) {
            bf16x8 af[4], bfr[4];
#pragma unroll
            for (int ti = 0; ti < 4; ti++) {
                const int rA = wr + ti * 16 + l15;
                af[ti] = *(const bf16x8*)(&As[rA][(((ks * 4 + quad) ^ (rA & 7)) * 8)]);
            }
#pragma unroll
            for (int tj = 0; tj < 4; tj++) {
                const int rB = wc + tj * 16 + l15;
                bfr[tj] = *(const bf16x8*)(&Bs[rB][(((ks * 4 + quad) ^ (rB & 7)) * 8)]);
            }
#pragma unroll
            for (int ti = 0; ti < 4; ti++)
#pragma unroll
                for (int tj = 0; tj < 4; tj++)
                    acc[ti][tj] = __builtin_amdgcn_mfma_f32_16x16x32_bf16(
                        af[ti], bfr[tj], acc[ti][tj], 0, 0, 0);
        }
    }

#pragma unroll
    for (int tj = 0; tj < 4; tj++) {
        const int col = colBase + wc + tj * 16 + l15;
        const float bv = __bfloat162float(bias[col]);
#pragma unroll
        for (int ti = 0; ti < 4; ti++) {
#pragma unroll
            for (int r = 0; r < 4; r++) {
                const int row = rowBase + wr + ti * 16 + quad * 4 + r;
                const float val = acc[ti][tj][r] + bv;
                if (mode) {
                    ((float*)out)[(size_t)row * EMB + col] = val;
                } else {
                    ((__hip_bfloat16*)out)[(size_t)row * EMB + col] = __float2bfloat16(val);
                }
            }
        }
    }
}

// ---------------------------------------------------------------------------
extern "C" void kernel_launch(void* const* d_in, const int* in_sizes, int n_in,
                              void* d_out, int out_size, void* d_ws, size_t ws_size,
                              hipStream_t stream) {
    const void* query = d_in[0];  // (2048,4,1024)
    const void* w_in  = d_in[1];  // (3072,1024)
    const void* b_in  = d_in[2];  // (3072,)
    const void* w_out = d_in[3];  // (1024,1024)
    const void* b_out = d_in[4];  // (1024,)

    char* ws = (char*)d_ws;
    int*            flag   = (int*)ws;
    __hip_bfloat16* Xc     = (__hip_bfloat16*)(ws + 256);
    __hip_bfloat16* Winc   = Xc   + (size_t)8192 * 1024;
    __hip_bfloat16* binc   = Winc + (size_t)3072 * 1024;
    __hip_bfloat16* Woutc  = binc + 3072;
    __hip_bfloat16* boutc  = Woutc + (size_t)1024 * 1024;
    __hip_bfloat16* Qws    = boutc + 1024;
    __hip_bfloat16* Kws    = Qws + (size_t)8388608;
    __hip_bfloat16* Vws    = Kws + (size_t)8388608;
    __hip_bfloat16* AOut   = Vws + (size_t)8388608;

    detect_kernel<<<1, 256, 0, stream>>>((const unsigned short*)query, flag);

    convert_all_kernel<<<2048, 256, 0, stream>>>(query, w_in, b_in, w_out, b_out,
                                                 Xc, Winc, binc, Woutc, boutc, flag);

    qkv_gemm_kernel<<<dim3(64, 24), 256, 0, stream>>>(Xc, Winc, binc, Qws, Kws, Vws);
    attn_kernel<<<dim3(64, 8), 256, 0, stream>>>(Qws, Kws, Vws, AOut);
    out_gemm_kernel<<<dim3(64, 8), 256, 0, stream>>>(AOut, Woutc, boutc, d_out, flag);
}

// Round 5
// 291.148 us; speedup vs baseline: 1.2126x; 1.2126x over previous
//
#include <hip/hip_runtime.h>
#include <hip/hip_bf16.h>

// MultiheadAttention: S=2048, B=4, E=1024, H=16, D=64
//   K0   detect input dtype (fp32 vs bf16) -> flag
//   K0b  single merged convert kernel -> canonical bf16 in ws
//   K1   qkv GEMM (m97-style).  Q pre-scaled by 0.125*log2(e)  (log2-domain softmax)
//   K2   flash attention (R0 structure, LDS-staged K/V) with SWAPPED QK^T:
//        S^T = mfma(A=K, B=Q) -> lane holds 4 CONSECUTIVE keys per q, so the
//        P tile is written with 8 ds_write_b64 instead of 32 ds_write_b16
//        (the LDS port was the saturated resource: ~460 cyc/wave-tile vs a
//        473-cyc budget).  All LDS reads identical to the proven R0 kernel.
//   K3   out-proj GEMM

typedef __attribute__((ext_vector_type(8))) short bf16x8;
typedef __attribute__((ext_vector_type(4))) float floatx4;

#define S_LEN 2048
#define EMB   1024
#define DHEAD 64

static __device__ __forceinline__ unsigned short f2bf(float x) {
    return __builtin_bit_cast(unsigned short, __float2bfloat16(x));
}

static __device__ __forceinline__ unsigned pack_bf16(float a, float b) {
    // dword[15:0] = bf16(a), dword[31:16] = bf16(b), RNE
    return (unsigned)f2bf(a) | ((unsigned)f2bf(b) << 16);
}

// ---------------------------------------------------------------------------
static __device__ __forceinline__ void dma16(const void* g, void* l) {
    __builtin_amdgcn_global_load_lds(
        (const __attribute__((address_space(1))) unsigned int*)(unsigned long long)g,
        (__attribute__((address_space(3))) unsigned int*)(unsigned int)(unsigned long long)l,
        16, 0, 0);
}

// ---------------------------------------------------------------------------
// K0: dtype detection (fp32 read as u16 words has ~48% with exponent>=132)
// ---------------------------------------------------------------------------
__global__ void detect_kernel(const unsigned short* __restrict__ q, int* __restrict__ flag) {
    __shared__ int cnt;
    if (threadIdx.x == 0) cnt = 0;
    __syncthreads();
    int local = 0;
    for (int i = threadIdx.x; i < 4096; i += 256) {
        unsigned short u = q[i];
        int e = (u >> 7) & 0xFF;
        if (e >= 132) local++;
    }
    atomicAdd(&cnt, local);
    __syncthreads();
    if (threadIdx.x == 0) *flag = (cnt > 100) ? 1 : 0;
}

// ---------------------------------------------------------------------------
// K0b: merged convert of all 5 inputs, vectorized x4.
// ---------------------------------------------------------------------------
__global__ void convert_all_kernel(
    const void* __restrict__ s0, const void* __restrict__ s1, const void* __restrict__ s2,
    const void* __restrict__ s3, const void* __restrict__ s4,
    __hip_bfloat16* __restrict__ d0, __hip_bfloat16* __restrict__ d1, __hip_bfloat16* __restrict__ d2,
    __hip_bfloat16* __restrict__ d3, __hip_bfloat16* __restrict__ d4,
    const int* __restrict__ flag)
{
    const int mode = *flag;
    const int c0 = 2097152, c1 = c0 + 786432, c2 = c1 + 768, c3 = c2 + 262144, c4 = c3 + 256;
    int i = blockIdx.x * blockDim.x + threadIdx.x;
    const int stride = gridDim.x * blockDim.x;
    for (; i < c4; i += stride) {
        const void* s; __hip_bfloat16* d; int off;
        if (i < c0)      { s = s0; d = d0; off = i; }
        else if (i < c1) { s = s1; d = d1; off = i - c0; }
        else if (i < c2) { s = s2; d = d2; off = i - c1; }
        else if (i < c3) { s = s3; d = d3; off = i - c2; }
        else             { s = s4; d = d4; off = i - c3; }
        if (mode) {
            float4 v = ((const float4*)s)[off];
            ushort4 o;
            o.x = f2bf(v.x); o.y = f2bf(v.y); o.z = f2bf(v.z); o.w = f2bf(v.w);
            ((ushort4*)d)[off] = o;
        } else {
            ((ushort4*)d)[off] = ((const ushort4*)s)[off];
        }
    }
}

// ---------------------------------------------------------------------------
// GEMM core (m97 structure): 128x128 tile, BK=64, XOR chunk swizzle LDS.
// ---------------------------------------------------------------------------
#define GEMM_STAGE(As, Bs, Aptr, Bptr, ldA, ldB)                                       \
    {                                                                                  \
        const int srow = (l >> 3);                                                     \
        const int cG   = ((l & 7) ^ srow) * 8;                                         \
        _Pragma("unroll")                                                              \
        for (int j = 0; j < 4; j++) {                                                  \
            const int r0 = wave * 32 + j * 8;                                          \
            dma16(Aptr + (size_t)(r0 + srow) * ldA + cG, &As[r0][0]);                  \
            dma16(Bptr + (size_t)(r0 + srow) * ldB + cG, &Bs[r0][0]);                  \
        }                                                                              \
    }

__global__ __launch_bounds__(256) void qkv_gemm_kernel(
    const __hip_bfloat16* __restrict__ X,
    const __hip_bfloat16* __restrict__ W,
    const __hip_bfloat16* __restrict__ bias,
    __hip_bfloat16* __restrict__ Qws,
    __hip_bfloat16* __restrict__ Kws,
    __hip_bfloat16* __restrict__ Vws)
{
    __shared__ alignas(16) __hip_bfloat16 As[128][64];
    __shared__ alignas(16) __hip_bfloat16 Bs[128][64];

    const int t    = threadIdx.x;
    const int l    = t & 63;
    const int wave = t >> 6;
    const int l15  = l & 15;
    const int quad = l >> 4;
    const int wr   = (wave >> 1) * 64;
    const int wc   = (wave & 1) * 64;
    const int rowBase = blockIdx.x * 128;
    const int colBase = blockIdx.y * 128;

    floatx4 acc[4][4] = {};

    for (int k0 = 0; k0 < EMB; k0 += 64) {
        __syncthreads();
        const __hip_bfloat16* Ap = X + (size_t)rowBase * EMB + k0;
        const __hip_bfloat16* Bp = W + (size_t)colBase * EMB + k0;
        GEMM_STAGE(As, Bs, Ap, Bp, EMB, EMB)
        __syncthreads();
#pragma unroll
        for (int ks = 0; ks < 2; ks++) {
            bf16x8 af[4], bfr[4];
#pragma unroll
            for (int ti = 0; ti < 4; ti++) {
                const int rA = wr + ti * 16 + l15;
                af[ti] = *(const bf16x8*)(&As[rA][(((ks * 4 + quad) ^ (rA & 7)) * 8)]);
            }
#pragma unroll
            for (int tj = 0; tj < 4; tj++) {
                const int rB = wc + tj * 16 + l15;
                bfr[tj] = *(const bf16x8*)(&Bs[rB][(((ks * 4 + quad) ^ (rB & 7)) * 8)]);
            }
#pragma unroll
            for (int ti = 0; ti < 4; ti++)
#pragma unroll
                for (int tj = 0; tj < 4; tj++)
                    acc[ti][tj] = __builtin_amdgcn_mfma_f32_16x16x32_bf16(
                        af[ti], bfr[tj], acc[ti][tj], 0, 0, 0);
        }
    }

    // Q scale: 1/sqrt(64) * log2(e)  (softmax runs in log2 domain)
    const float QSCALE = 0.125f * 1.44269504088896f;
#pragma unroll
    for (int tj = 0; tj < 4; tj++) {
        const int col = colBase + wc + tj * 16 + l15;   // f in [0,3072)
        const int sec = col >> 10;                      // 0=Q 1=K 2=V
        const int e   = col & 1023;
        const int h   = e >> 6;
        const int d   = e & 63;
        const float bv = __bfloat162float(bias[col]);
#pragma unroll
        for (int ti = 0; ti < 4; ti++) {
#pragma unroll
            for (int r = 0; r < 4; r++) {
                const int row = rowBase + wr + ti * 16 + quad * 4 + r;  // s*4+b
                const int s  = row >> 2;
                const int b  = row & 3;
                const int nh = b * 16 + h;
                const float val = acc[ti][tj][r] + bv;
                if (sec == 0) {
                    Qws[((size_t)nh * S_LEN + s) * DHEAD + d] = __float2bfloat16(val * QSCALE);
                } else if (sec == 1) {
                    Kws[((size_t)nh * S_LEN + s) * DHEAD + d] = __float2bfloat16(val);
                } else {
                    Vws[((size_t)nh * DHEAD + d) * S_LEN + s] = __float2bfloat16(val);
                }
            }
        }
    }
}

// ---------------------------------------------------------------------------
// K2: flash attention (R0 layout), swapped QK^T, b64 P-writes.
// Block = (head n, 128 q-rows), 4 waves x 32 q each.
//
// QK^T: S^T = mfma(A=K_frag, B=Q_frag) — A/B frags share the same lane
// mapping (l15, k=quad*8+j), so the LDS reads are IDENTICAL to R0; only the
// intrinsic operand order and the C interpretation change:
//   C (HW-verified m89/m91): col = l15 = q, row = quad*4+r = key (within nt).
// Lane thus holds 4 consecutive keys for one q -> pack to ONE ds_write_b64 at
// Ps[q][nt*16+quad*4].  PV reads Ps[q][ks*32+quad*8] b128 — unchanged.
// Denominator: per-lane partial for q=l15; reduced once at epilogue with
// 2 shfl_xor + a 512B LDS redistribution to the C-layout lanes.
// ---------------------------------------------------------------------------
__global__ __launch_bounds__(256, 4) void attn_kernel(
    const __hip_bfloat16* __restrict__ Qws,
    const __hip_bfloat16* __restrict__ Kws,
    const __hip_bfloat16* __restrict__ Vws,
    __hip_bfloat16* __restrict__ AOut)
{
    __shared__ alignas(16) __hip_bfloat16 Ks[64][64];    // [key][d], swizzled
    __shared__ alignas(16) __hip_bfloat16 Vts[64][64];   // [d][key], swizzled
    __shared__ alignas(16) __hip_bfloat16 Ps[4][32][72]; // per-wave P, padded
    __shared__ float Ls[4][32];                          // per-wave 1/denom

    const int n  = blockIdx.x;        // 0..63
    const int q0 = blockIdx.y * 128;
    const int t    = threadIdx.x;
    const int l    = t & 63;
    const int wave = t >> 6;
    const int l15  = l & 15;
    const int quad = l >> 4;

    // Q fragments straight from global (row=l15 -> q, k=quad*8+j)
    bf16x8 qa[2][2];
#pragma unroll
    for (int qs = 0; qs < 2; qs++)
#pragma unroll
        for (int ks = 0; ks < 2; ks++)
            qa[qs][ks] = *(const bf16x8*)(Qws +
                ((size_t)n * S_LEN + q0 + wave * 32 + qs * 16 + l15) * DHEAD + ks * 32 + quad * 8);

    floatx4 o[2][4] = {};
    float lsum[2] = {};   // per-lane partial denominator for q = qs*16+l15

    const int srow = (l >> 3);
    const int cG   = ((l & 7) ^ srow) * 8;

    for (int kt = 0; kt < 32; kt++) {
        __syncthreads();
        const int key0 = kt * 64;
#pragma unroll
        for (int j = 0; j < 2; j++) {
            const int r0 = wave * 16 + j * 8;
            dma16(Kws + ((size_t)n * S_LEN + key0 + r0 + srow) * DHEAD + cG, &Ks[r0][0]);
            dma16(Vws + ((size_t)n * DHEAD + r0 + srow) * S_LEN + key0 + cG, &Vts[r0][0]);
        }
        __syncthreads();

        // QK^T swapped: sacc[qs][nt] = S^T tile, col=q=l15, row=key=quad*4+r
        floatx4 sacc[2][4] = {};
#pragma unroll
        for (int ks = 0; ks < 2; ks++) {
#pragma unroll
            for (int nt = 0; nt < 4; nt++) {
                const int rK = nt * 16 + l15;
                bf16x8 kb = *(const bf16x8*)(&Ks[rK][(((ks * 4 + quad) ^ (rK & 7)) * 8)]);
#pragma unroll
                for (int qs = 0; qs < 2; qs++)
                    sacc[qs][nt] = __builtin_amdgcn_mfma_f32_16x16x32_bf16(
                        kb, qa[qs][ks], sacc[qs][nt], 0, 0, 0);
            }
        }

        // softmax: p = exp2(s) native; scores already log2-domain via QSCALE.
        // Lane holds keys nt*16+quad*4+{0..3} for q=qs*16+l15 -> one b64 write.
#pragma unroll
        for (int qs = 0; qs < 2; qs++) {
#pragma unroll
            for (int nt = 0; nt < 4; nt++) {
                const float p0 = __builtin_amdgcn_exp2f(sacc[qs][nt][0]);
                const float p1 = __builtin_amdgcn_exp2f(sacc[qs][nt][1]);
                const float p2 = __builtin_amdgcn_exp2f(sacc[qs][nt][2]);
                const float p3 = __builtin_amdgcn_exp2f(sacc[qs][nt][3]);
                lsum[qs] += (p0 + p1) + (p2 + p3);
                uint2 w;
                w.x = pack_bf16(p0, p1);
                w.y = pack_bf16(p2, p3);
                *(uint2*)(&Ps[wave][qs * 16 + l15][nt * 16 + quad * 4]) = w;
            }
        }
        // no barrier: Ps[wave] is wave-private

        // PV: O(32x64) += P(32x64) @ V(64x64)   (reads identical to R0)
        bf16x8 pa[2][2];
#pragma unroll
        for (int qs = 0; qs < 2; qs++)
#pragma unroll
            for (int ks = 0; ks < 2; ks++)
                pa[qs][ks] = *(const bf16x8*)(&Ps[wave][qs * 16 + l15][ks * 32 + quad * 8]);
#pragma unroll
        for (int ks = 0; ks < 2; ks++) {
#pragma unroll
            for (int nt = 0; nt < 4; nt++) {
                const int rV = nt * 16 + l15;
                bf16x8 vb = *(const bf16x8*)(&Vts[rV][(((ks * 4 + quad) ^ (rV & 7)) * 8)]);
#pragma unroll
                for (int qs = 0; qs < 2; qs++)
                    o[qs][nt] = __builtin_amdgcn_mfma_f32_16x16x32_bf16(
                        pa[qs][ks], vb, o[qs][nt], 0, 0, 0);
            }
        }
    }

    // epilogue: reduce lsum (held per q=l15) across the 4 quad-lanes, then
    // redistribute 1/denom to the C-layout lanes (q = quad*4+r) via tiny LDS.
#pragma unroll
    for (int qs = 0; qs < 2; qs++) {
        float dsum = lsum[qs] + __shfl_xor(lsum[qs], 16);
        dsum += __shfl_xor(dsum, 32);
        if (quad == 0) Ls[wave][qs * 16 + l15] = 1.0f / dsum;
    }

    const int bb  = n >> 4;
    const int h64 = (n & 15) * 64;
#pragma unroll
    for (int qs = 0; qs < 2; qs++) {
        const float4 lv = *(const float4*)(&Ls[wave][qs * 16 + quad * 4]);
#pragma unroll
        for (int r = 0; r < 4; r++) {
            const float linv = ((const float*)&lv)[r];
#pragma unroll
            for (int nt = 0; nt < 4; nt++) {
                const int q = q0 + wave * 32 + qs * 16 + quad * 4 + r;
                const int d = nt * 16 + l15;
                AOut[((size_t)q * 4 + bb) * EMB + h64 + d] = __float2bfloat16(o[qs][nt][r] * linv);
            }
        }
    }
}

// ---------------------------------------------------------------------------
// K3: out-projection GEMM, output fp32 or bf16 per flag.
// ---------------------------------------------------------------------------
__global__ __launch_bounds__(256) void out_gemm_kernel(
    const __hip_bfloat16* __restrict__ A,
    const __hip_bfloat16* __restrict__ W,
    const __hip_bfloat16* __restrict__ bias,
    void* __restrict__ out,
    const int* __restrict__ flag)
{
    __shared__ alignas(16) __hip_bfloat16 As[128][64];
    __shared__ alignas(16) __hip_bfloat16 Bs[128][64];

    const int t    = threadIdx.x;
    const int l    = t & 63;
    const int wave = t >> 6;
    const int l15  = l & 15;
    const int quad = l >> 4;
    const int wr   = (wave >> 1) * 64;
    const int wc   = (wave & 1) * 64;
    const int rowBase = blockIdx.x * 128;
    const int colBase = blockIdx.y * 128;
    const int mode = *flag;

    floatx4 acc[4][4] = {};

    for (int k0 = 0; k0 < EMB; k0 += 64) {
        __syncthreads();
        const __hip_bfloat16* Ap = A + (size_t)rowBase * EMB + k0;
        const __hip_bfloat16* Bp = W + (size_t)colBase * EMB + k0;
        GEMM_STAGE(As, Bs, Ap, Bp, EMB, EMB)
        __syncthreads();
#pragma unroll
        for (int ks = 0; ks < 2; ks++) {
            bf16x8 af[4], bfr[4];
#pragma unroll
            for (int ti = 0; ti < 4; ti++) {
                const int rA = wr + ti * 16 + l15;
                af[ti] = *(const bf16x8*)(&As[rA][(((ks * 4 + quad) ^ (rA & 7)) * 8)]);
            }
#pragma unroll
            for (int tj = 0; tj < 4; tj++) {
                const int rB = wc + tj * 16 + l15;
                bfr[tj] = *(const bf16x8*)(&Bs[rB][(((ks * 4 + quad) ^ (rB & 7)) * 8)]);
            }
#pragma unroll
            for (int ti = 0; ti < 4; ti++)
#pragma unroll
                for (int tj = 0; tj < 4; tj++)
                    acc[ti][tj] = __builtin_amdgcn_mfma_f32_16x16x32_bf16(
                        af[ti], bfr[tj], acc[ti][tj], 0, 0, 0);
        }
    }

#pragma unroll
    for (int tj = 0; tj < 4; tj++) {
        const int col = colBase + wc + tj * 16 + l15;
        const float bv = __bfloat162float(bias[col]);
#pragma unroll
        for (int ti = 0; ti < 4; ti++) {
#pragma unroll
            for (int r = 0; r < 4; r++) {
                const int row = rowBase + wr + ti * 16 + quad * 4 + r;
                const float val = acc[ti][tj][r] + bv;
                if (mode) {
                    ((float*)out)[(size_t)row * EMB + col] = val;
                } else {
                    ((__hip_bfloat16*)out)[(size_t)row * EMB + col] = __float2bfloat16(val);
                }
            }
        }
    }
}

// ---------------------------------------------------------------------------
extern "C" void kernel_launch(void* const* d_in, const int* in_sizes, int n_in,
                              void* d_out, int out_size, void* d_ws, size_t ws_size,
                              hipStream_t stream) {
    const void* query = d_in[0];  // (2048,4,1024)
    const void* w_in  = d_in[1];  // (3072,1024)
    const void* b_in  = d_in[2];  // (3072,)
    const void* w_out = d_in[3];  // (1024,1024)
    const void* b_out = d_in[4];  // (1024,)

    char* ws = (char*)d_ws;
    int*            flag   = (int*)ws;
    __hip_bfloat16* Xc     = (__hip_bfloat16*)(ws + 256);
    __hip_bfloat16* Winc   = Xc   + (size_t)8192 * 1024;
    __hip_bfloat16* binc   = Winc + (size_t)3072 * 1024;
    __hip_bfloat16* Woutc  = binc + 3072;
    __hip_bfloat16* boutc  = Woutc + (size_t)1024 * 1024;
    __hip_bfloat16* Qws    = boutc + 1024;
    __hip_bfloat16* Kws    = Qws + (size_t)8388608;
    __hip_bfloat16* Vws    = Kws + (size_t)8388608;
    __hip_bfloat16* AOut   = Vws + (size_t)8388608;

    detect_kernel<<<1, 256, 0, stream>>>((const unsigned short*)query, flag);

    convert_all_kernel<<<2048, 256, 0, stream>>>(query, w_in, b_in, w_out, b_out,
                                                 Xc, Winc, binc, Woutc, boutc, flag);

    qkv_gemm_kernel<<<dim3(64, 24), 256, 0, stream>>>(Xc, Winc, binc, Qws, Kws, Vws);
    attn_kernel<<<dim3(64, 16), 256, 0, stream>>>(Qws, Kws, Vws, AOut);
    out_gemm_kernel<<<dim3(64, 8), 256, 0, stream>>>(AOut, Woutc, boutc, d_out, flag);
}